// Round 2
// baseline (1373.144 us; speedup 1.0000x reference)
//
#include <hip/hip_runtime.h>
#include <hip/hip_bf16.h>

// Problem constants (StaticRecurrentEntNet): B=256,S=32,L=32,D=256,E=64,VOCAB=50000
#define Bb 256
#define Ss 32
#define Ll 32
#define Dd 256
#define Ee 64

__device__ __forceinline__ float bf2f(unsigned int u16) {
    return __uint_as_float(u16 << 16);
}
__device__ __forceinline__ unsigned short f2bf(float f) {
    unsigned int x = __float_as_uint(f);
    unsigned int r = (x + 0x7fffu + ((x >> 16) & 1u)) >> 16;   // RNE
    return (unsigned short)r;
}

// ---------------- Kernel A: enc[bs][d] = sum_l emb[tok[bs][l]][d]*mask[bs][l]; active[bs]
__global__ void k_enc(const int* __restrict__ tok, const float* __restrict__ mask,
                      const float* __restrict__ emb, float* __restrict__ enc,
                      int* __restrict__ act) {
    int bs = blockIdx.x;            // 0..B*S-1
    int d  = threadIdx.x;           // 0..255
    const int*   t = tok  + (long)bs * Ll;
    const float* m = mask + (long)bs * Ll;
    float acc = 0.f;
    #pragma unroll 4
    for (int l = 0; l < Ll; ++l) {
        acc += emb[(long)t[l] * Dd + d] * m[l];
    }
    enc[(long)bs * Dd + d] = acc;
    if (d == 0) {
        float s = 0.f;
        for (int l = 0; l < Ll; ++l) s += m[l];
        act[bs] = (s > 0.f) ? 1 : 0;
    }
}

// ---------------- Kernel B: Y[rows][256] = X[rows][256] @ M[256][256]  (fp32)
// 16 rows per block; block = 256 threads = 64 colgroups(4 cols) x 4 rowquarters(4 rows)
__global__ void k_rowmat(const float* __restrict__ X, const float* __restrict__ M,
                         float* __restrict__ Y) {
    __shared__ __align__(16) float xs[16 * Dd];
    int tid = threadIdx.x;
    long row0 = (long)blockIdx.x * 16;
    #pragma unroll
    for (int i = 0; i < 16; ++i) xs[i * Dd + tid] = X[(row0 + i) * Dd + tid];
    __syncthreads();
    int cg = tid & 63;   // cols cg*4 .. +3
    int rq = tid >> 6;   // rows rq*4 .. +3
    float acc[4][4];
    #pragma unroll
    for (int r = 0; r < 4; ++r)
        #pragma unroll
        for (int c = 0; c < 4; ++c) acc[r][c] = 0.f;
    for (int d = 0; d < Dd; ++d) {
        float4 mv = *reinterpret_cast<const float4*>(&M[d * Dd + cg * 4]);
        #pragma unroll
        for (int r = 0; r < 4; ++r) {
            float x = xs[(rq * 4 + r) * Dd + d];
            acc[r][0] += x * mv.x; acc[r][1] += x * mv.y;
            acc[r][2] += x * mv.z; acc[r][3] += x * mv.w;
        }
    }
    #pragma unroll
    for (int r = 0; r < 4; ++r) {
        float4 o = make_float4(acc[r][0], acc[r][1], acc[r][2], acc[r][3]);
        *reinterpret_cast<float4*>(&Y[(row0 + rq * 4 + r) * Dd + cg * 4]) = o;
    }
}

// ---------------- Kernel Bgk: gk[bs][e] = dot(enc[bs], keys[b][e]),  b = bs/S
__global__ void k_gk(const float* __restrict__ enc, const float* __restrict__ keys,
                     float* __restrict__ gk) {
    int bs = blockIdx.x;
    int b  = bs >> 5;               // S = 32
    __shared__ __align__(16) float es[Dd];
    int tid = threadIdx.x;
    es[tid] = enc[(long)bs * Dd + tid];
    __syncthreads();
    int e = tid >> 2, q = tid & 3;
    const float* kr = keys + ((long)b * Ee + e) * Dd;
    float p = 0.f;
    #pragma unroll 8
    for (int i = 0; i < 64; ++i) {
        int d = q + 4 * i;
        p += es[d] * kr[d];
    }
    p += __shfl_xor(p, 1);
    p += __shfl_xor(p, 2);
    if (q == 0) gk[(long)bs * Ee + e] = p;
}

// ---------------- Kernel D: the 32-step recurrence, one block per b, h resident.
// block 256 threads: tc = tid&31 -> cols tc*8..+7 ; tr = tid>>5 -> rows tr*8..+7
__global__ __launch_bounds__(256) void k_scan(
    const float* __restrict__ enc, const int* __restrict__ act,
    const float* __restrict__ gk,  const float* __restrict__ kv,
    const float* __restrict__ eWm, const float* __restrict__ U,
    float* __restrict__ out) {
    __shared__ __align__(16) unsigned short hbf[Dd * Ee];  // [d][r] bf16 mirror, swizzled, 32KB
    __shared__ __align__(16) float Uc[16 * Dd];            // U k-chunk stage, 16KB
    __shared__ __align__(16) float es[Dd];
    __shared__ float ghs[Ee];
    __shared__ float gs[Ee];
    __shared__ float rn[Ee];

    int tid = threadIdx.x;
    int b   = blockIdx.x;
    int tc  = tid & 31;
    int tr  = tid >> 5;

    float h[8][8];
    #pragma unroll
    for (int r = 0; r < 8; ++r)
        #pragma unroll
        for (int c = 0; c < 8; ++c) h[r][c] = 0.f;

    for (int i = tid; i < Dd * Ee; i += 256) hbf[i] = 0;

    const float* kvp = kv + (long)b * Ee * Dd;

    for (int s = 0; s < Ss; ++s) {
        int bs = b * Ss + s;
        es[tid] = enc[(long)bs * Dd + tid];
        int a = act[bs];                       // uniform per block
        __syncthreads();                       // es ready (also covers hbf init at s=0)

        // ---- g-dot: p[r] = dot(es, h_row) partial over this thread's 8 cols
        float4 e0 = *reinterpret_cast<const float4*>(&es[tc * 8]);
        float4 e1 = *reinterpret_cast<const float4*>(&es[tc * 8 + 4]);
        float p[8];
        #pragma unroll
        for (int r = 0; r < 8; ++r) {
            p[r] = h[r][0] * e0.x + h[r][1] * e0.y + h[r][2] * e0.z + h[r][3] * e0.w
                 + h[r][4] * e1.x + h[r][5] * e1.y + h[r][6] * e1.z + h[r][7] * e1.w;
        }
        #pragma unroll
        for (int r = 0; r < 8; ++r) {
            p[r] += __shfl_xor(p[r], 16);
            p[r] += __shfl_xor(p[r], 8);
            p[r] += __shfl_xor(p[r], 4);
            p[r] += __shfl_xor(p[r], 2);
            p[r] += __shfl_xor(p[r], 1);
        }
        if (tc == 0) {
            #pragma unroll
            for (int r = 0; r < 8; ++r) ghs[tr * 8 + r] = p[r];
        }
        __syncthreads();
        if (tid < Ee) {
            float x = ghs[tid] + gk[(long)bs * Ee + tid];
            gs[tid] = 1.f / (1.f + expf(-x));
        }

        // ---- GEMM: acc[r][c] = sum_d h_bf16[row][d] * U[d][col]
        float acc[8][8];
        #pragma unroll
        for (int r = 0; r < 8; ++r)
            #pragma unroll
            for (int c = 0; c < 8; ++c) acc[r][c] = 0.f;

        for (int kk = 0; kk < Dd; kk += 16) {
            __syncthreads();                   // Uc free to overwrite; also publishes gs (kk==0)
            #pragma unroll
            for (int i = 0; i < 16; ++i) Uc[i * Dd + tid] = U[(kk + i) * Dd + tid];
            __syncthreads();
            #pragma unroll
            for (int k2 = 0; k2 < 16; ++k2) {
                int d = kk + k2;
                int sw = ((d ^ (d >> 3)) & 7) << 4;
                const uint4* ap = reinterpret_cast<const uint4*>(
                    reinterpret_cast<const char*>(hbf) + (((d << 7) + (tr << 4)) ^ sw));
                uint4 av = *ap;
                float ar[8];
                ar[0] = bf2f(av.x & 0xffffu); ar[1] = bf2f(av.x >> 16);
                ar[2] = bf2f(av.y & 0xffffu); ar[3] = bf2f(av.y >> 16);
                ar[4] = bf2f(av.z & 0xffffu); ar[5] = bf2f(av.z >> 16);
                ar[6] = bf2f(av.w & 0xffffu); ar[7] = bf2f(av.w >> 16);
                float4 u0 = *reinterpret_cast<const float4*>(&Uc[k2 * Dd + tc * 8]);
                float4 u1 = *reinterpret_cast<const float4*>(&Uc[k2 * Dd + tc * 8 + 4]);
                float uv[8] = {u0.x, u0.y, u0.z, u0.w, u1.x, u1.y, u1.z, u1.w};
                #pragma unroll
                for (int r = 0; r < 8; ++r)
                    #pragma unroll
                    for (int c = 0; c < 8; ++c) acc[r][c] += ar[r] * uv[c];
            }
        }

        // ---- epilogue: h_t = relu(acc + kv + eW); h_new = h + g*h_t; normalize
        {
            const float* ewp = eWm + (long)bs * Dd + tc * 8;
            float4 w0 = *reinterpret_cast<const float4*>(ewp);
            float4 w1 = *reinterpret_cast<const float4*>(ewp + 4);
            float ew[8] = {w0.x, w0.y, w0.z, w0.w, w1.x, w1.y, w1.z, w1.w};
            float sq[8];
            #pragma unroll
            for (int r = 0; r < 8; ++r) {
                const float* kr = kvp + (long)(tr * 8 + r) * Dd + tc * 8;
                float4 k0 = *reinterpret_cast<const float4*>(kr);
                float4 k1 = *reinterpret_cast<const float4*>(kr + 4);
                float kvv[8] = {k0.x, k0.y, k0.z, k0.w, k1.x, k1.y, k1.z, k1.w};
                float g = gs[tr * 8 + r];
                float sp = 0.f;
                #pragma unroll
                for (int c = 0; c < 8; ++c) {
                    float ht = acc[r][c] + kvv[c] + ew[c];
                    ht = fmaxf(ht, 0.f);
                    float v = h[r][c] + g * ht;
                    acc[r][c] = v;              // reuse acc as h_new
                    sp += v * v;
                }
                sq[r] = sp;
            }
            #pragma unroll
            for (int r = 0; r < 8; ++r) {
                sq[r] += __shfl_xor(sq[r], 16);
                sq[r] += __shfl_xor(sq[r], 8);
                sq[r] += __shfl_xor(sq[r], 4);
                sq[r] += __shfl_xor(sq[r], 2);
                sq[r] += __shfl_xor(sq[r], 1);
            }
            if (tc == 0) {
                #pragma unroll
                for (int r = 0; r < 8; ++r)
                    rn[tr * 8 + r] = rsqrtf(fmaxf(sq[r], 1e-12f));
            }
        }
        __syncthreads();                       // rn visible; hbf reads done
        if (a) {
            #pragma unroll
            for (int r = 0; r < 8; ++r) {
                float rr = rn[tr * 8 + r];
                #pragma unroll
                for (int c = 0; c < 8; ++c) h[r][c] = acc[r][c] * rr;
            }
            #pragma unroll
            for (int c = 0; c < 8; ++c) {
                int d = tc * 8 + c;
                unsigned int w0 = (unsigned)f2bf(h[0][c]) | ((unsigned)f2bf(h[1][c]) << 16);
                unsigned int w1 = (unsigned)f2bf(h[2][c]) | ((unsigned)f2bf(h[3][c]) << 16);
                unsigned int w2 = (unsigned)f2bf(h[4][c]) | ((unsigned)f2bf(h[5][c]) << 16);
                unsigned int w3 = (unsigned)f2bf(h[6][c]) | ((unsigned)f2bf(h[7][c]) << 16);
                int sw = ((d ^ (d >> 3)) & 7) << 4;
                uint4* wp = reinterpret_cast<uint4*>(
                    reinterpret_cast<char*>(hbf) + (((d << 7) + (tr << 4)) ^ sw));
                *wp = make_uint4(w0, w1, w2, w3);
            }
        }
        __syncthreads();                       // hbf updated before next step
    }

    // write back h (fp32) -> out[(b*E + e)*D + d]
    #pragma unroll
    for (int r = 0; r < 8; ++r) {
        float4 o0 = make_float4(h[r][0], h[r][1], h[r][2], h[r][3]);
        float4 o1 = make_float4(h[r][4], h[r][5], h[r][6], h[r][7]);
        float* op = out + ((long)b * Ee + tr * 8 + r) * Dd + tc * 8;
        *reinterpret_cast<float4*>(op)     = o0;
        *reinterpret_cast<float4*>(op + 4) = o1;
    }
}

extern "C" void kernel_launch(void* const* d_in, const int* in_sizes, int n_in,
                              void* d_out, int out_size, void* d_ws, size_t ws_size,
                              hipStream_t stream) {
    const int*   tok  = (const int*)d_in[0];    // (B,S,L) int32
    const float* mask = (const float*)d_in[1];  // (B,S,L) f32
    const float* keys = (const float*)d_in[2];  // (B,E,D) f32
    const float* emb  = (const float*)d_in[3];  // (VOCAB,D) f32
    const float* U    = (const float*)d_in[4];  // (D,D)
    const float* V    = (const float*)d_in[5];  // (D,D)
    const float* W    = (const float*)d_in[6];  // (D,D)
    float* out = (float*)d_out;

    // workspace layout (floats)
    float* enc = (float*)d_ws;                    // B*S*D      = 2,097,152
    float* kv  = enc + (long)Bb * Ss * Dd;        // B*E*D      = 4,194,304
    float* eW  = kv  + (long)Bb * Ee * Dd;        // B*S*D      = 2,097,152
    float* gkv = eW  + (long)Bb * Ss * Dd;        // B*S*E      =   524,288
    int*   act = (int*)(gkv + (long)Bb * Ss * Ee);// B*S        =     8,192

    k_enc<<<Bb * Ss, Dd, 0, stream>>>(tok, mask, emb, enc, act);
    k_rowmat<<<(Bb * Ee) / 16, 256, 0, stream>>>(keys, V, kv);   // kv = keys @ V
    k_rowmat<<<(Bb * Ss) / 16, 256, 0, stream>>>(enc, W, eW);    // eW = enc @ W
    k_gk<<<Bb * Ss, 256, 0, stream>>>(enc, keys, gkv);           // gk = dot(enc, keys)
    k_scan<<<Bb, 256, 0, stream>>>(enc, act, gkv, kv, eW, U, out);
}

// Round 3
// 573.746 us; speedup vs baseline: 2.3933x; 2.3933x over previous
//
#include <hip/hip_runtime.h>
#include <hip/hip_bf16.h>

// Problem constants (StaticRecurrentEntNet): B=256,S=32,L=32,D=256,E=64,VOCAB=50000
#define Bb 256
#define Ss 32
#define Ll 32
#define Dd 256
#define Ee 64

typedef __attribute__((ext_vector_type(8))) short short8v;
typedef __attribute__((ext_vector_type(4))) float float4v;

__device__ __forceinline__ unsigned short f2bf(float f) {
    unsigned int x = __float_as_uint(f);
    unsigned int r = (x + 0x7fffu + ((x >> 16) & 1u)) >> 16;   // RNE
    return (unsigned short)r;
}

// ---------------- Kernel A: enc[bs][d] = sum_l emb[tok[bs][l]][d]*mask[bs][l]; active[bs]
__global__ void k_enc(const int* __restrict__ tok, const float* __restrict__ mask,
                      const float* __restrict__ emb, float* __restrict__ enc,
                      int* __restrict__ act) {
    int bs = blockIdx.x;            // 0..B*S-1
    int d  = threadIdx.x;           // 0..255
    const int*   t = tok  + (long)bs * Ll;
    const float* m = mask + (long)bs * Ll;
    float acc = 0.f;
    #pragma unroll 4
    for (int l = 0; l < Ll; ++l) {
        acc += emb[(long)t[l] * Dd + d] * m[l];
    }
    enc[(long)bs * Dd + d] = acc;
    if (d == 0) {
        float s = 0.f;
        for (int l = 0; l < Ll; ++l) s += m[l];
        act[bs] = (s > 0.f) ? 1 : 0;
    }
}

// ---------------- Kernel B: Y[rows][256] = X[rows][256] @ M[256][256]  (fp32)
__global__ void k_rowmat(const float* __restrict__ X, const float* __restrict__ M,
                         float* __restrict__ Y) {
    __shared__ __align__(16) float xs[16 * Dd];
    int tid = threadIdx.x;
    long row0 = (long)blockIdx.x * 16;
    #pragma unroll
    for (int i = 0; i < 16; ++i) xs[i * Dd + tid] = X[(row0 + i) * Dd + tid];
    __syncthreads();
    int cg = tid & 63;   // cols cg*4 .. +3
    int rq = tid >> 6;   // rows rq*4 .. +3
    float acc[4][4];
    #pragma unroll
    for (int r = 0; r < 4; ++r)
        #pragma unroll
        for (int c = 0; c < 4; ++c) acc[r][c] = 0.f;
    for (int d = 0; d < Dd; ++d) {
        float4 mv = *reinterpret_cast<const float4*>(&M[d * Dd + cg * 4]);
        #pragma unroll
        for (int r = 0; r < 4; ++r) {
            float x = xs[(rq * 4 + r) * Dd + d];
            acc[r][0] += x * mv.x; acc[r][1] += x * mv.y;
            acc[r][2] += x * mv.z; acc[r][3] += x * mv.w;
        }
    }
    #pragma unroll
    for (int r = 0; r < 4; ++r) {
        float4 o = make_float4(acc[r][0], acc[r][1], acc[r][2], acc[r][3]);
        *reinterpret_cast<float4*>(&Y[(row0 + rq * 4 + r) * Dd + cg * 4]) = o;
    }
}

// ---------------- Kernel Bgk: gk[bs][e] = dot(enc[bs], keys[b][e]),  b = bs/S
__global__ void k_gk(const float* __restrict__ enc, const float* __restrict__ keys,
                     float* __restrict__ gk) {
    int bs = blockIdx.x;
    int b  = bs >> 5;               // S = 32
    __shared__ __align__(16) float es[Dd];
    int tid = threadIdx.x;
    es[tid] = enc[(long)bs * Dd + tid];
    __syncthreads();
    int e = tid >> 2, q = tid & 3;
    const float* kr = keys + ((long)b * Ee + e) * Dd;
    float p = 0.f;
    #pragma unroll 8
    for (int i = 0; i < 64; ++i) {
        int d = q + 4 * i;
        p += es[d] * kr[d];
    }
    p += __shfl_xor(p, 1);
    p += __shfl_xor(p, 2);
    if (q == 0) gk[(long)bs * Ee + e] = p;
}

// ---------------- Kernel D: 32-step recurrence, MFMA version.
// One block per b. 4 waves; wave w owns output cols [w*64, w*64+64).
// Wave tile: 64 rows (entities) x 64 cols. U bf16 B-fragments live in
// registers for the whole kernel (128 VGPR). h fp32 lives in C-layout
// registers; a swizzled bf16 LDS mirror feeds the MFMA A-operand.
// C/D layout (m89): col = lane&15, row = (lane>>4)*4 + reg.
// A layout: row = lane&15, k = (lane>>4)*8 + i.  B: col = lane&15, same k.
__global__ __launch_bounds__(256, 1) void k_scan(
    const float* __restrict__ enc, const int* __restrict__ act,
    const float* __restrict__ gk,  const float* __restrict__ kv,
    const float* __restrict__ eWm, const float* __restrict__ U,
    float* __restrict__ out) {
    __shared__ __align__(16) unsigned short hbf[Ee * Dd];  // [row][k] bf16, swizzled, 32KB
    __shared__ float part[4][Ee];
    __shared__ float gs[Ee];
    __shared__ float rn[Ee];

    const int tid = threadIdx.x;
    const int b   = blockIdx.x;
    const int w   = tid >> 6;       // wave id: cols w*64..+63
    const int l   = tid & 63;
    const int q   = l >> 4;         // quarter
    const int sl  = l & 15;

    // zero h mirror
    for (int i = tid; i < (Ee * Dd) / 2; i += 256)
        reinterpret_cast<unsigned int*>(hbf)[i] = 0u;

    // ---- preload U B-fragments (held in registers all 32 steps) ----
    short8v bU[8][4];
    #pragma unroll
    for (int kk = 0; kk < 8; ++kk)
        #pragma unroll
        for (int ni = 0; ni < 4; ++ni) {
            const int n = w * 64 + ni * 16 + sl;
            #pragma unroll
            for (int i = 0; i < 8; ++i) {
                const int k = kk * 32 + q * 8 + i;
                bU[kk][ni][i] = (short)f2bf(U[k * Dd + n]);
            }
        }

    // ---- preload kv (loop-invariant additive term), C-layout ----
    float kvr[4][4][4];
    #pragma unroll
    for (int mi = 0; mi < 4; ++mi)
        #pragma unroll
        for (int ni = 0; ni < 4; ++ni)
            #pragma unroll
            for (int j = 0; j < 4; ++j) {
                const int r = mi * 16 + q * 4 + j;
                const int c = w * 64 + ni * 16 + sl;
                kvr[mi][ni][j] = kv[((long)b * Ee + r) * Dd + c];
            }

    float h[4][4][4];
    #pragma unroll
    for (int mi = 0; mi < 4; ++mi)
        #pragma unroll
        for (int ni = 0; ni < 4; ++ni)
            #pragma unroll
            for (int j = 0; j < 4; ++j) h[mi][ni][j] = 0.f;

    // prefetch es for step 0
    float es_c[4];
    #pragma unroll
    for (int ni = 0; ni < 4; ++ni)
        es_c[ni] = enc[(long)(b * Ss) * Dd + w * 64 + ni * 16 + sl];

    __syncthreads();   // hbf zero-init visible before first GEMM

    for (int s = 0; s < Ss; ++s) {
        const long bs = (long)b * Ss + s;
        const int  a  = act[bs];                       // uniform per block
        const float gkv = gk[bs * Ee + (tid & 63)];    // used by tid<64 after B1

        // ---- eW loads early: consumed in epilogue, hidden under GEMM ----
        float ew[4];
        #pragma unroll
        for (int ni = 0; ni < 4; ++ni)
            ew[ni] = eWm[bs * Dd + w * 64 + ni * 16 + sl];

        // ---- g-dot: per-row dot(es, h) over this wave's 64 cols ----
        #pragma unroll
        for (int mi = 0; mi < 4; ++mi)
            #pragma unroll
            for (int j = 0; j < 4; ++j) {
                float p = es_c[0] * h[mi][0][j] + es_c[1] * h[mi][1][j]
                        + es_c[2] * h[mi][2][j] + es_c[3] * h[mi][3][j];
                p += __shfl_xor(p, 1);
                p += __shfl_xor(p, 2);
                p += __shfl_xor(p, 4);
                p += __shfl_xor(p, 8);
                if (sl == 0) part[w][mi * 16 + q * 4 + j] = p;
            }
        __syncthreads();                               // B1: part ready; hbf writes (s-1) done
        if (tid < Ee) {
            const float x = part[0][tid] + part[1][tid] + part[2][tid] + part[3][tid] + gkv;
            gs[tid] = 1.f / (1.f + expf(-x));
        }

        // ---- GEMM: acc = h_bf16 @ U  (A from LDS, B from registers) ----
        float4v acc[4][4];
        #pragma unroll
        for (int mi = 0; mi < 4; ++mi)
            #pragma unroll
            for (int ni = 0; ni < 4; ++ni) acc[mi][ni] = (float4v)0.f;

        #pragma unroll
        for (int kk = 0; kk < 8; ++kk) {
            short8v av[4];
            #pragma unroll
            for (int mi = 0; mi < 4; ++mi) {
                const int row = mi * 16 + sl;
                const int off = ((row << 9) + (kk << 6) + (q << 4)) ^ ((row & 7) << 4);
                av[mi] = *reinterpret_cast<const short8v*>(
                    reinterpret_cast<const char*>(hbf) + off);
            }
            #pragma unroll
            for (int mi = 0; mi < 4; ++mi)
                #pragma unroll
                for (int ni = 0; ni < 4; ++ni)
                    acc[mi][ni] = __builtin_amdgcn_mfma_f32_16x16x32_bf16(
                        av[mi], bU[kk][ni], acc[mi][ni], 0, 0, 0);
        }
        __syncthreads();                               // B2: gs visible; hbf reads done

        // ---- epilogue: h_new = h + g*relu(acc + kv + eW); row sumsq ----
        #pragma unroll
        for (int mi = 0; mi < 4; ++mi)
            #pragma unroll
            for (int j = 0; j < 4; ++j) {
                const float g = gs[mi * 16 + q * 4 + j];
                float sp = 0.f;
                #pragma unroll
                for (int ni = 0; ni < 4; ++ni) {
                    float ht = acc[mi][ni][j] + kvr[mi][ni][j] + ew[ni];
                    ht = fmaxf(ht, 0.f);
                    const float v = h[mi][ni][j] + g * ht;
                    acc[mi][ni][j] = v;                // acc now holds unnormalized h_new
                    sp += v * v;
                }
                sp += __shfl_xor(sp, 1);
                sp += __shfl_xor(sp, 2);
                sp += __shfl_xor(sp, 4);
                sp += __shfl_xor(sp, 8);
                if (sl == 0) part[w][mi * 16 + q * 4 + j] = sp;
            }
        __syncthreads();                               // B3
        if (tid < Ee) {
            const float t = part[0][tid] + part[1][tid] + part[2][tid] + part[3][tid];
            rn[tid] = rsqrtf(fmaxf(t, 1e-12f));
        }
        __syncthreads();                               // B4: rn visible

        // ---- commit (only if sentence active) + refresh bf16 mirror ----
        if (a) {
            #pragma unroll
            for (int mi = 0; mi < 4; ++mi)
                #pragma unroll
                for (int j = 0; j < 4; ++j) {
                    const int r  = mi * 16 + q * 4 + j;
                    const float rr = rn[r];
                    #pragma unroll
                    for (int ni = 0; ni < 4; ++ni) {
                        const float v = acc[mi][ni][j] * rr;
                        h[mi][ni][j] = v;
                        const int c   = w * 64 + ni * 16 + sl;
                        const int off = ((r << 9) + (c << 1)) ^ ((r & 7) << 4);
                        *reinterpret_cast<unsigned short*>(
                            reinterpret_cast<char*>(hbf) + off) = f2bf(v);
                    }
                }
        }

        // prefetch next step's es while others still writing hbf
        if (s + 1 < Ss) {
            #pragma unroll
            for (int ni = 0; ni < 4; ++ni)
                es_c[ni] = enc[(bs + 1) * Dd + w * 64 + ni * 16 + sl];
        }
        // no barrier here: next iteration's B1 orders hbf writes vs GEMM reads
    }

    // ---- write back h (fp32) -> out[(b*E + r)*D + c] ----
    #pragma unroll
    for (int mi = 0; mi < 4; ++mi)
        #pragma unroll
        for (int ni = 0; ni < 4; ++ni)
            #pragma unroll
            for (int j = 0; j < 4; ++j) {
                const int r = mi * 16 + q * 4 + j;
                const int c = w * 64 + ni * 16 + sl;
                out[((long)b * Ee + r) * Dd + c] = h[mi][ni][j];
            }
}

extern "C" void kernel_launch(void* const* d_in, const int* in_sizes, int n_in,
                              void* d_out, int out_size, void* d_ws, size_t ws_size,
                              hipStream_t stream) {
    const int*   tok  = (const int*)d_in[0];    // (B,S,L) int32
    const float* mask = (const float*)d_in[1];  // (B,S,L) f32
    const float* keys = (const float*)d_in[2];  // (B,E,D) f32
    const float* emb  = (const float*)d_in[3];  // (VOCAB,D) f32
    const float* U    = (const float*)d_in[4];  // (D,D)
    const float* V    = (const float*)d_in[5];  // (D,D)
    const float* W    = (const float*)d_in[6];  // (D,D)
    float* out = (float*)d_out;

    // workspace layout (floats)
    float* enc = (float*)d_ws;                    // B*S*D      = 2,097,152
    float* kv  = enc + (long)Bb * Ss * Dd;        // B*E*D      = 4,194,304
    float* eW  = kv  + (long)Bb * Ee * Dd;        // B*S*D      = 2,097,152
    float* gkv = eW  + (long)Bb * Ss * Dd;        // B*S*E      =   524,288
    int*   act = (int*)(gkv + (long)Bb * Ss * Ee);// B*S        =     8,192

    k_enc<<<Bb * Ss, Dd, 0, stream>>>(tok, mask, emb, enc, act);
    k_rowmat<<<(Bb * Ee) / 16, 256, 0, stream>>>(keys, V, kv);   // kv = keys @ V
    k_rowmat<<<(Bb * Ss) / 16, 256, 0, stream>>>(enc, W, eW);    // eW = enc @ W
    k_gk<<<Bb * Ss, 256, 0, stream>>>(enc, keys, gkv);           // gk = dot(enc, keys)
    k_scan<<<Bb, 256, 0, stream>>>(enc, act, gkv, kv, eW, U, out);
}